// Round 1
// 29397.705 us; speedup vs baseline: 1.8272x; 1.8272x over previous
//
#include <hip/hip_runtime.h>
#include <stdint.h>

typedef unsigned short u16;
typedef unsigned int   u32;
using bf16x8 = __attribute__((ext_vector_type(8))) short;
using f32x4  = __attribute__((ext_vector_type(4))) float;

#define T_LEN 2048
#define BATCH 32
#define FDIM  512
#define HDIM  512
#define GDIM  1536
#define WG_PER_DIR 16
#define SLICE 32           // h indices per WG
#define NROWS 96           // real gate rows per WG (3 gates x SLICE)
#define LSTR  520          // LDS row stride in u16: 1040B, 16B-aligned

__device__ __forceinline__ u16 f2bf(float f) {
  union { float f; u32 u; } v; v.f = f;
  u32 r = v.u + 0x7fffu + ((v.u >> 16) & 1u);
  return (u16)(r >> 16);
}

__global__ void convert_kernel(const float* __restrict__ src, u16* __restrict__ dst, int n4) {
  int i = blockIdx.x * blockDim.x + threadIdx.x;
  int stride = gridDim.x * blockDim.x;
  for (; i < n4; i += stride) {
    float4 v = ((const float4*)src)[i];
    ushort4 o;
    o.x = f2bf(v.x); o.y = f2bf(v.y); o.z = f2bf(v.z); o.w = f2bf(v.w);
    ((ushort4*)dst)[i] = o;
  }
}

// 16 WGs per direction (was 64). Each WG: 512 threads = 8 waves.
// Wave w owns N-tile w (16 gate-cols); waves 0..5 cover the 96 real rows,
// waves 6,7 idle during MFMA but help stage/gates. Each wave computes BOTH
// M-tiles (batch 0-15, 16-31) so weights are NOT duplicated across waves.
// Sync: per-WG flag word (own 128B line), RELEASE store by producer,
// consumer wave0 polls all 16 flags with one 16-lane load + ballot.
__launch_bounds__(512, 2)
__global__ void gru_scan(
    const u16* __restrict__ xbf,                               // [T][B][F] bf16
    const u16* __restrict__ wihF, const u16* __restrict__ whhF, // [G][K] bf16
    const u16* __restrict__ wihR, const u16* __restrict__ whhR,
    const float* __restrict__ bihF, const float* __restrict__ bhhF,
    const float* __restrict__ bihR, const float* __restrict__ bhhR,
    const float* __restrict__ h0,                              // [2][B][H] f32
    u16* __restrict__ hbuf,                                    // [2 buf][2 dir][B][H] bf16
    float* __restrict__ out,                                   // y [T][B][2H] + states [2][B][H]
    u32* __restrict__ flags)                                   // [2 dir][16 wg] u32, 128B apart
{
  const int wg   = blockIdx.x;
  const int dir  = wg >> 4;
  const int wgl  = wg & 15;
  const int hbase = wgl * SLICE;
  const int tid  = threadIdx.x;
  const int lane = tid & 63;
  const int wave = tid >> 6;
  const int nt   = wave;           // N-tile (gate-col block of 16); 0..5 real

  const u16*  wih = dir ? wihR : wihF;
  const u16*  whh = dir ? whhR : whhF;
  const float* bih = dir ? bihR : bihF;
  const float* bhh = dir ? bhhR : bhhF;

  __shared__ u16   buf[32 * LSTR];     // staged A operand (x_t, then h_t)
  __shared__ float s_gi[32][100];
  __shared__ float s_gh[32][100];
  __shared__ float s_hold[32][SLICE];  // fp32 resident h slice
  __shared__ float s_bih[NROWS];
  __shared__ float s_bhh[NROWS];

  // ---- preload weight B-fragments into registers (stay for whole scan) ----
  bf16x8 wfi[16], wfh[16];
  {
    const int nloc = nt * 16 + (lane & 15);   // 0..127; >=96 is pad (waves 6,7)
    const int kq   = (lane >> 4) * 8;         // k sub-offset within 32-wide K step
    if (nloc < NROWS) {
      const int g = (nloc >> 5) * HDIM + hbase + (nloc & 31);  // gate*512 + h index
      const u16* pih = wih + (size_t)g * FDIM + kq;
      const u16* phh = whh + (size_t)g * HDIM + kq;
#pragma unroll
      for (int kk = 0; kk < 16; ++kk) {
        wfi[kk] = *(const bf16x8*)(pih + kk * 32);
        wfh[kk] = *(const bf16x8*)(phh + kk * 32);
      }
    } else {
      bf16x8 z = {};
#pragma unroll
      for (int kk = 0; kk < 16; ++kk) { wfi[kk] = z; wfh[kk] = z; }
    }
  }

  if (tid < NROWS) {
    const int g = (tid >> 5) * HDIM + hbase + (tid & 31);
    s_bih[tid] = bih[g];
    s_bhh[tid] = bhh[g];
  }

  // ---- init resident h slice + publish h_0 (bf16) ----
#pragma unroll
  for (int i = 0; i < 2; ++i) {
    const int idx = tid + 512 * i;            // 1024 = 32b x 32h values
    const int b = idx >> 5, hh = idx & 31;
    float v = h0[(dir * BATCH + b) * HDIM + hbase + hh];
    s_hold[b][hh] = v;
    hbuf[(size_t)dir * (BATCH * HDIM) + b * HDIM + hbase + hh] = f2bf(v);
  }
  __threadfence();
  __syncthreads();
  u32* myflag = flags + (dir * WG_PER_DIR + wgl) * 32;
  if (tid == 0)
    __hip_atomic_store(myflag, 1u, __ATOMIC_RELEASE, __HIP_MEMORY_SCOPE_AGENT);

  const int koff = (lane >> 4) * 8;
  const u16* ab0 = buf + (lane & 15) * LSTR + koff;   // A-frag base, M-tile 0

  for (int t = 0; t < T_LEN; ++t) {
    // ======== phase 1: x_t staging + ih-GEMM (independent of h_t, hides sync) ========
    const int tx = dir ? (T_LEN - 1 - t) : t;
    const u16* xsrc = xbf + (size_t)tx * (BATCH * FDIM);
#pragma unroll
    for (int j = 0; j < 4; ++j) {
      const int c = tid + 512 * j;         // 2048 chunks of 16B
      const int row = c >> 6;
      const int col = (c & 63) * 8;
      *(bf16x8*)(buf + row * LSTR + col) = *(const bf16x8*)(xsrc + row * FDIM + col);
    }
    __syncthreads();

    if (nt < 6) {
      f32x4 acc0 = {0.f, 0.f, 0.f, 0.f};
      f32x4 acc1 = {0.f, 0.f, 0.f, 0.f};
#pragma unroll
      for (int kk = 0; kk < 16; ++kk) {
        bf16x8 a0 = *(const bf16x8*)(ab0 + kk * 32);
        bf16x8 a1 = *(const bf16x8*)(ab0 + 16 * LSTR + kk * 32);
        acc0 = __builtin_amdgcn_mfma_f32_16x16x32_bf16(a0, wfi[kk], acc0, 0, 0, 0);
        acc1 = __builtin_amdgcn_mfma_f32_16x16x32_bf16(a1, wfi[kk], acc1, 0, 0, 0);
      }
      const int col = nt * 16 + (lane & 15);
      const int rb  = (lane >> 4) << 2;
#pragma unroll
      for (int r = 0; r < 4; ++r) {
        s_gi[rb + r][col]      = acc0[r];
        s_gi[16 + rb + r][col] = acc1[r];
      }
    }
    __syncthreads();  // gi dumped, buf reads complete

    // ======== phase 2: wait for h_t (wave0 polls 16 flag lines in one load) ========
    if (wave == 0) {
      const u32 target = (u32)(t + 1);
      const u32* fl = flags + dir * WG_PER_DIR * 32;
      for (;;) {
        u32 v = 0xFFFFFFFFu;
        if (lane < WG_PER_DIR)
          v = __hip_atomic_load(fl + lane * 32, __ATOMIC_RELAXED, __HIP_MEMORY_SCOPE_AGENT);
        if (__ballot(v >= target) == 0xFFFFFFFFFFFFFFFFull) break;
        __builtin_amdgcn_s_sleep(1);
      }
    }
    __syncthreads();
    __threadfence();  // acquire: see remote hbuf writes

    // ======== phase 3: h_t staging + hh-GEMM ========
    const u16* hsrc = hbuf + ((size_t)(t & 1) * 2 + dir) * (BATCH * HDIM);
#pragma unroll
    for (int j = 0; j < 4; ++j) {
      const int c = tid + 512 * j;
      const int row = c >> 6;
      const int col = (c & 63) * 8;
      *(bf16x8*)(buf + row * LSTR + col) = *(const bf16x8*)(hsrc + row * HDIM + col);
    }
    __syncthreads();

    if (nt < 6) {
      f32x4 acc0 = {0.f, 0.f, 0.f, 0.f};
      f32x4 acc1 = {0.f, 0.f, 0.f, 0.f};
#pragma unroll
      for (int kk = 0; kk < 16; ++kk) {
        bf16x8 a0 = *(const bf16x8*)(ab0 + kk * 32);
        bf16x8 a1 = *(const bf16x8*)(ab0 + 16 * LSTR + kk * 32);
        acc0 = __builtin_amdgcn_mfma_f32_16x16x32_bf16(a0, wfh[kk], acc0, 0, 0, 0);
        acc1 = __builtin_amdgcn_mfma_f32_16x16x32_bf16(a1, wfh[kk], acc1, 0, 0, 0);
      }
      const int col = nt * 16 + (lane & 15);
      const int rb  = (lane >> 4) << 2;
#pragma unroll
      for (int r = 0; r < 4; ++r) {
        s_gh[rb + r][col]      = acc0[r];
        s_gh[16 + rb + r][col] = acc1[r];
      }
    }
    __syncthreads();

    // ======== phase 4: gates + state update (fp32), publish h_{t+1} ========
#pragma unroll
    for (int i = 0; i < 2; ++i) {
      const int idx = tid + 512 * i;
      const int b = idx >> 5, hh = idx & 31;
      const float rx = s_gi[b][hh]      + s_bih[hh];
      const float zx = s_gi[b][32 + hh] + s_bih[32 + hh];
      const float nx = s_gi[b][64 + hh] + s_bih[64 + hh];
      const float rh = s_gh[b][hh]      + s_bhh[hh];
      const float zh = s_gh[b][32 + hh] + s_bhh[32 + hh];
      const float nh = s_gh[b][64 + hh] + s_bhh[64 + hh];
      const float r = 1.f / (1.f + __expf(-(rx + rh)));
      const float z = 1.f / (1.f + __expf(-(zx + zh)));
      const float n = tanhf(nx + r * nh);
      const float hnew = (1.f - z) * n + z * s_hold[b][hh];
      s_hold[b][hh] = hnew;
      out[((size_t)t * BATCH + b) * (2 * HDIM) + dir * HDIM + hbase + hh] = hnew;
      hbuf[((size_t)((t + 1) & 1) * 2 + dir) * (BATCH * HDIM) + b * HDIM + hbase + hh] = f2bf(hnew);
    }

    // arrive: h_{t+1} visible, then independent RELEASE store (no RMW contention)
    __threadfence();
    __syncthreads();
    if (tid == 0)
      __hip_atomic_store(myflag, (u32)(t + 2), __ATOMIC_RELEASE, __HIP_MEMORY_SCOPE_AGENT);
  }

  // ---- final states: [1,2,B,H] appended after y ----
#pragma unroll
  for (int i = 0; i < 2; ++i) {
    const int idx = tid + 512 * i;
    const int b = idx >> 5, hh = idx & 31;
    out[(size_t)T_LEN * BATCH * 2 * HDIM + (size_t)(dir * BATCH + b) * HDIM + hbase + hh] =
        s_hold[b][hh];
  }
}

extern "C" void kernel_launch(void* const* d_in, const int* in_sizes, int n_in,
                              void* d_out, int out_size, void* d_ws, size_t ws_size,
                              hipStream_t stream) {
  const float* x    = (const float*)d_in[0];
  const float* h0   = (const float*)d_in[1];
  const float* wihF = (const float*)d_in[2];
  const float* bihF = (const float*)d_in[3];
  const float* whhF = (const float*)d_in[4];
  const float* bhhF = (const float*)d_in[5];
  const float* wihR = (const float*)d_in[6];
  const float* bihR = (const float*)d_in[7];
  const float* whhR = (const float*)d_in[8];
  const float* bhhR = (const float*)d_in[9];

  const size_t NX = (size_t)T_LEN * BATCH * FDIM;   // 33,554,432 elements
  const size_t NW = (size_t)GDIM * FDIM;            // 786,432 elements

  char* ws   = (char*)d_ws;
  u16* xbf   = (u16*)ws;
  u16* wihFb = (u16*)(ws + NX * 2);
  u16* whhFb = wihFb + NW;
  u16* wihRb = whhFb + NW;
  u16* whhRb = wihRb + NW;
  u16* hbuf  = whhRb + NW;                          // 2*2*32*512 u16 = 128KB
  u32* flags = (u32*)((char*)(hbuf + 4 * BATCH * HDIM));  // 2*16 u32, 128B apart

  hipMemsetAsync(flags, 0, 4096, stream);
  convert_kernel<<<2048, 256, 0, stream>>>(x,    xbf,   (int)(NX / 4));
  convert_kernel<<<256,  256, 0, stream>>>(wihF, wihFb, (int)(NW / 4));
  convert_kernel<<<256,  256, 0, stream>>>(whhF, whhFb, (int)(NW / 4));
  convert_kernel<<<256,  256, 0, stream>>>(wihR, wihRb, (int)(NW / 4));
  convert_kernel<<<256,  256, 0, stream>>>(whhR, whhRb, (int)(NW / 4));

  gru_scan<<<2 * WG_PER_DIR, 512, 0, stream>>>(xbf, wihFb, whhFb, wihRb, whhRb,
                                               bihF, bhhF, bihR, bhhR,
                                               h0, hbuf, (float*)d_out, flags);
}

// Round 2
// 9384.695 us; speedup vs baseline: 5.7239x; 3.1325x over previous
//
#include <hip/hip_runtime.h>
#include <stdint.h>

typedef unsigned short u16;
typedef unsigned int   u32;
using bf16x8 = __attribute__((ext_vector_type(8))) short;
using f32x4  = __attribute__((ext_vector_type(4))) float;

#define T_LEN 2048
#define BATCH 32
#define FDIM  512
#define HDIM  512
#define GDIM  1536
#define WG_PER_DIR 16
#define SLICE 32           // h indices per WG
#define NROWS 96           // real gate rows per WG (3 gates x SLICE)

__device__ __forceinline__ u16 f2bf(float f) {
  union { float f; u32 u; } v; v.f = f;
  u32 r = v.u + 0x7fffu + ((v.u >> 16) & 1u);
  return (u16)(r >> 16);
}

__global__ void convert_kernel(const float* __restrict__ src, u16* __restrict__ dst, int n4) {
  int i = blockIdx.x * blockDim.x + threadIdx.x;
  int stride = gridDim.x * blockDim.x;
  for (; i < n4; i += stride) {
    float4 v = ((const float4*)src)[i];
    ushort4 o;
    o.x = f2bf(v.x); o.y = f2bf(v.y); o.z = f2bf(v.z); o.w = f2bf(v.w);
    ((ushort4*)dst)[i] = o;
  }
}

// Cross-WG mailbox via per-access coherent (sc0 sc1) ops at the IF coherence
// point: NO cache-wide fences (wbl2/inv) per step, so x_t stays L2-resident.
// LDS staging buffer uses linear 1024B rows + XOR swizzle ((row&7)<<4) for
// conflict-free ds_read_b128 MFMA fragment reads.
__launch_bounds__(512, 2)
__global__ void gru_scan(
    const u16* __restrict__ xbf,                               // [T][B][F] bf16
    const u16* __restrict__ wihF, const u16* __restrict__ whhF, // [G][K] bf16
    const u16* __restrict__ wihR, const u16* __restrict__ whhR,
    const float* __restrict__ bihF, const float* __restrict__ bhhF,
    const float* __restrict__ bihR, const float* __restrict__ bhhR,
    const float* __restrict__ h0,                              // [2][B][H] f32
    u16* __restrict__ hbuf,                                    // [2 buf][2 dir][B][H] bf16
    float* __restrict__ out,                                   // y [T][B][2H] + states [2][B][H]
    u32* __restrict__ flags)                                   // [2 dir][16 wg] u32, 128B apart
{
  const int wg   = blockIdx.x;
  const int dir  = wg >> 4;
  const int wgl  = wg & 15;
  const int hbase = wgl * SLICE;
  const int tid  = threadIdx.x;
  const int lane = tid & 63;
  const int wave = tid >> 6;
  const int nt   = wave;           // N-tile (gate-col block of 16); 0..5 real

  const u16*  wih = dir ? wihR : wihF;
  const u16*  whh = dir ? whhR : whhF;
  const float* bih = dir ? bihR : bihF;
  const float* bhh = dir ? bhhR : bhhF;

  __shared__ u16   buf[32 * 512];      // staged A operand, 1024B rows, XOR-swizzled
  __shared__ float s_gi[32][100];
  __shared__ float s_gh[32][100];
  __shared__ float s_hold[32][SLICE];  // fp32 resident h slice
  __shared__ float s_bih[NROWS];
  __shared__ float s_bhh[NROWS];

  // ---- preload weight B-fragments into registers (stay for whole scan) ----
  bf16x8 wfi[16], wfh[16];
  {
    const int nloc = nt * 16 + (lane & 15);   // 0..127; >=96 is pad (waves 6,7)
    const int kq   = (lane >> 4) * 8;         // k sub-offset within 32-wide K step
    if (nloc < NROWS) {
      const int g = (nloc >> 5) * HDIM + hbase + (nloc & 31);  // gate*512 + h index
      const u16* pih = wih + (size_t)g * FDIM + kq;
      const u16* phh = whh + (size_t)g * HDIM + kq;
#pragma unroll
      for (int kk = 0; kk < 16; ++kk) {
        wfi[kk] = *(const bf16x8*)(pih + kk * 32);
        wfh[kk] = *(const bf16x8*)(phh + kk * 32);
      }
    } else {
      bf16x8 z = {};
#pragma unroll
      for (int kk = 0; kk < 16; ++kk) { wfi[kk] = z; wfh[kk] = z; }
    }
  }

  if (tid < NROWS) {
    const int g = (tid >> 5) * HDIM + hbase + (tid & 31);
    s_bih[tid] = bih[g];
    s_bhh[tid] = bhh[g];
  }

  // per-thread gate-phase mapping: batch gb, two adjacent h (gh2, gh2+1)
  const int gb  = tid >> 4;
  const int gh2 = (tid & 15) * 2;

  // ---- init resident h slice + publish h_0 (bf16, coherent) ----
  {
    const float* hp = h0 + (size_t)(dir * BATCH + gb) * HDIM + hbase + gh2;
    float v0 = hp[0], v1 = hp[1];
    s_hold[gb][gh2]     = v0;
    s_hold[gb][gh2 + 1] = v1;
    u32 packed = (u32)f2bf(v0) | ((u32)f2bf(v1) << 16);
    u16* dst = hbuf + (size_t)dir * (BATCH * HDIM) + gb * HDIM + hbase + gh2;
    asm volatile("global_store_dword %0, %1, off sc0 sc1" :: "v"(dst), "v"(packed) : "memory");
  }
  asm volatile("s_waitcnt vmcnt(0)" ::: "memory");
  __syncthreads();
  u32* myflag = flags + (dir * WG_PER_DIR + wgl) * 32;
  if (tid == 0) {
    u32 one = 1u;
    asm volatile("global_store_dword %0, %1, off sc0 sc1" :: "v"(myflag), "v"(one) : "memory");
  }

  // MFMA A-fragment addressing (swizzled):
  // logical byte = r0*1024 + kk*64 + kq16 ; swizzled ^= (r0&7)<<4
  // = r0*1024 + (kq16 ^ ((r0&3)<<4)) + ((kk ^ kx)<<6), kx = (r0>>2)&1
  const int r0   = lane & 15;
  const int kq16 = (lane >> 4) * 16;
  const int kx   = (r0 >> 2) & 1;
  const char* abase = (const char*)buf + r0 * 1024 + (kq16 ^ ((r0 & 3) << 4));
  const char* aE = abase + (kx << 6);   // even kk
  const char* aO = abase - (kx << 6);   // odd kk

  // staging addressing for this thread (4 rows: row0, +8, +16, +24)
  const int row0 = tid >> 6;
  const int cb   = (tid & 63) * 16;            // byte col within 1024B row
  const int cbx  = cb ^ ((row0 & 7) << 4);     // (row+8k)&7 identical for all 4

  for (int t = 0; t < T_LEN; ++t) {
    // ======== phase 1: x_t staging (cached) + ih-GEMM ========
    const int tx = dir ? (T_LEN - 1 - t) : t;
    const u16* xsrc = xbf + (size_t)tx * (BATCH * FDIM);
#pragma unroll
    for (int j = 0; j < 4; ++j) {
      const int row = row0 + 8 * j;
      bf16x8 v = *(const bf16x8*)(xsrc + row * FDIM + (cb >> 1));
      *(bf16x8*)((char*)buf + row * 1024 + cbx) = v;
    }
    __syncthreads();

    if (nt < 6) {
      f32x4 acc0 = {0.f, 0.f, 0.f, 0.f};
      f32x4 acc1 = {0.f, 0.f, 0.f, 0.f};
#pragma unroll
      for (int kk = 0; kk < 16; ++kk) {
        const char* ap = (kk & 1) ? aO : aE;
        bf16x8 a0 = *(const bf16x8*)(ap + kk * 64);
        bf16x8 a1 = *(const bf16x8*)(ap + 16 * 1024 + kk * 64);
        acc0 = __builtin_amdgcn_mfma_f32_16x16x32_bf16(a0, wfi[kk], acc0, 0, 0, 0);
        acc1 = __builtin_amdgcn_mfma_f32_16x16x32_bf16(a1, wfi[kk], acc1, 0, 0, 0);
      }
      const int col = nt * 16 + (lane & 15);
      const int rb  = (lane >> 4) << 2;
#pragma unroll
      for (int r = 0; r < 4; ++r) {
        s_gi[rb + r][col]      = acc0[r];
        s_gi[16 + rb + r][col] = acc1[r];
      }
    }
    __syncthreads();  // gi dumped, buf reads complete

    // ======== phase 2: wait for h_t (coherent flag poll, no fences) ========
    if (wave == 0) {
      const u32 target = (u32)(t + 1);
      const u32* fl = flags + dir * WG_PER_DIR * 32;
      const u32* fa = fl + (lane & 15) * 32;
      for (;;) {
        u32 v;
        asm volatile("global_load_dword %0, %1, off sc0 sc1\n\ts_waitcnt vmcnt(0)"
                     : "=v"(v) : "v"(fa) : "memory");
        if (__ballot(v >= target) == ~0ull) break;
        __builtin_amdgcn_s_sleep(1);
      }
    }
    __syncthreads();

    // ======== phase 3: h_t staging (coherent bundle) + hh-GEMM ========
    const u16* hsrc = hbuf + ((size_t)(t & 1) * 2 + dir) * (BATCH * HDIM);
    {
      bf16x8 hv0, hv1, hv2, hv3;
      const u16* p0 = hsrc + (row0     ) * HDIM + (cb >> 1);
      const u16* p1 = hsrc + (row0 + 8 ) * HDIM + (cb >> 1);
      const u16* p2 = hsrc + (row0 + 16) * HDIM + (cb >> 1);
      const u16* p3 = hsrc + (row0 + 24) * HDIM + (cb >> 1);
      asm volatile(
        "global_load_dwordx4 %0, %4, off sc0 sc1\n\t"
        "global_load_dwordx4 %1, %5, off sc0 sc1\n\t"
        "global_load_dwordx4 %2, %6, off sc0 sc1\n\t"
        "global_load_dwordx4 %3, %7, off sc0 sc1\n\t"
        "s_waitcnt vmcnt(0)"
        : "=&v"(hv0), "=&v"(hv1), "=&v"(hv2), "=&v"(hv3)
        : "v"(p0), "v"(p1), "v"(p2), "v"(p3)
        : "memory");
      __builtin_amdgcn_sched_barrier(0);
      *(bf16x8*)((char*)buf + (row0     ) * 1024 + cbx) = hv0;
      *(bf16x8*)((char*)buf + (row0 + 8 ) * 1024 + cbx) = hv1;
      *(bf16x8*)((char*)buf + (row0 + 16) * 1024 + cbx) = hv2;
      *(bf16x8*)((char*)buf + (row0 + 24) * 1024 + cbx) = hv3;
    }
    __syncthreads();

    if (nt < 6) {
      f32x4 acc0 = {0.f, 0.f, 0.f, 0.f};
      f32x4 acc1 = {0.f, 0.f, 0.f, 0.f};
#pragma unroll
      for (int kk = 0; kk < 16; ++kk) {
        const char* ap = (kk & 1) ? aO : aE;
        bf16x8 a0 = *(const bf16x8*)(ap + kk * 64);
        bf16x8 a1 = *(const bf16x8*)(ap + 16 * 1024 + kk * 64);
        acc0 = __builtin_amdgcn_mfma_f32_16x16x32_bf16(a0, wfh[kk], acc0, 0, 0, 0);
        acc1 = __builtin_amdgcn_mfma_f32_16x16x32_bf16(a1, wfh[kk], acc1, 0, 0, 0);
      }
      const int col = nt * 16 + (lane & 15);
      const int rb  = (lane >> 4) << 2;
#pragma unroll
      for (int r = 0; r < 4; ++r) {
        s_gh[rb + r][col]      = acc0[r];
        s_gh[16 + rb + r][col] = acc1[r];
      }
    }
    __syncthreads();

    // ======== phase 4: gates + state update (fp32), coherent publish ========
    {
      const float2 gir = *(const float2*)&s_gi[gb][gh2];
      const float2 giz = *(const float2*)&s_gi[gb][32 + gh2];
      const float2 gin = *(const float2*)&s_gi[gb][64 + gh2];
      const float2 ghr = *(const float2*)&s_gh[gb][gh2];
      const float2 ghz = *(const float2*)&s_gh[gb][32 + gh2];
      const float2 ghn = *(const float2*)&s_gh[gb][64 + gh2];
      const float2 bir = *(const float2*)&s_bih[gh2];
      const float2 biz = *(const float2*)&s_bih[32 + gh2];
      const float2 bin = *(const float2*)&s_bih[64 + gh2];
      const float2 bhr = *(const float2*)&s_bhh[gh2];
      const float2 bhz = *(const float2*)&s_bhh[32 + gh2];
      const float2 bhn = *(const float2*)&s_bhh[64 + gh2];
      const float2 hold = *(const float2*)&s_hold[gb][gh2];

      const float r0g = 1.f / (1.f + __expf(-((gir.x + bir.x) + (ghr.x + bhr.x))));
      const float r1g = 1.f / (1.f + __expf(-((gir.y + bir.y) + (ghr.y + bhr.y))));
      const float z0g = 1.f / (1.f + __expf(-((giz.x + biz.x) + (ghz.x + bhz.x))));
      const float z1g = 1.f / (1.f + __expf(-((giz.y + biz.y) + (ghz.y + bhz.y))));
      const float n0g = tanhf((gin.x + bin.x) + r0g * (ghn.x + bhn.x));
      const float n1g = tanhf((gin.y + bin.y) + r1g * (ghn.y + bhn.y));
      const float h0n = (1.f - z0g) * n0g + z0g * hold.x;
      const float h1n = (1.f - z1g) * n1g + z1g * hold.y;
      s_hold[gb][gh2]     = h0n;
      s_hold[gb][gh2 + 1] = h1n;
      float2 onew; onew.x = h0n; onew.y = h1n;
      *(float2*)&out[((size_t)t * BATCH + gb) * (2 * HDIM) + dir * HDIM + hbase + gh2] = onew;
      u32 packed = (u32)f2bf(h0n) | ((u32)f2bf(h1n) << 16);
      u16* dst = hbuf + ((size_t)((t + 1) & 1) * 2 + dir) * (BATCH * HDIM)
                      + gb * HDIM + hbase + gh2;
      asm volatile("global_store_dword %0, %1, off sc0 sc1" :: "v"(dst), "v"(packed) : "memory");
    }

    // arrive: h_{t+1} at coherence point, then flag (no wbl2 needed)
    asm volatile("s_waitcnt vmcnt(0)" ::: "memory");
    __syncthreads();
    if (tid == 0) {
      u32 val = (u32)(t + 2);
      asm volatile("global_store_dword %0, %1, off sc0 sc1" :: "v"(myflag), "v"(val) : "memory");
    }
  }

  // ---- final states: [1,2,B,H] appended after y ----
  {
    float2 fin;
    fin.x = s_hold[gb][gh2];
    fin.y = s_hold[gb][gh2 + 1];
    *(float2*)&out[(size_t)T_LEN * BATCH * 2 * HDIM
                   + (size_t)(dir * BATCH + gb) * HDIM + hbase + gh2] = fin;
  }
}

extern "C" void kernel_launch(void* const* d_in, const int* in_sizes, int n_in,
                              void* d_out, int out_size, void* d_ws, size_t ws_size,
                              hipStream_t stream) {
  const float* x    = (const float*)d_in[0];
  const float* h0   = (const float*)d_in[1];
  const float* wihF = (const float*)d_in[2];
  const float* bihF = (const float*)d_in[3];
  const float* whhF = (const float*)d_in[4];
  const float* bhhF = (const float*)d_in[5];
  const float* wihR = (const float*)d_in[6];
  const float* bihR = (const float*)d_in[7];
  const float* whhR = (const float*)d_in[8];
  const float* bhhR = (const float*)d_in[9];

  const size_t NX = (size_t)T_LEN * BATCH * FDIM;   // 33,554,432 elements
  const size_t NW = (size_t)GDIM * FDIM;            // 786,432 elements

  char* ws   = (char*)d_ws;
  u16* xbf   = (u16*)ws;
  u16* wihFb = (u16*)(ws + NX * 2);
  u16* whhFb = wihFb + NW;
  u16* wihRb = whhFb + NW;
  u16* whhRb = wihRb + NW;
  u16* hbuf  = whhRb + NW;                          // 2*2*32*512 u16 = 128KB
  u32* flags = (u32*)((char*)(hbuf + 4 * BATCH * HDIM));  // 2*16 u32, 128B apart

  hipMemsetAsync(flags, 0, 4096, stream);
  convert_kernel<<<2048, 256, 0, stream>>>(x,    xbf,   (int)(NX / 4));
  convert_kernel<<<256,  256, 0, stream>>>(wihF, wihFb, (int)(NW / 4));
  convert_kernel<<<256,  256, 0, stream>>>(whhF, whhFb, (int)(NW / 4));
  convert_kernel<<<256,  256, 0, stream>>>(wihR, wihRb, (int)(NW / 4));
  convert_kernel<<<256,  256, 0, stream>>>(whhR, whhRb, (int)(NW / 4));

  gru_scan<<<2 * WG_PER_DIR, 512, 0, stream>>>(xbf, wihFb, whhFb, wihRb, whhRb,
                                               bihF, bhhF, bihR, bhhR,
                                               h0, hbuf, (float*)d_out, flags);
}